// Round 1
// baseline (399.237 us; speedup 1.0000x reference)
//
#include <hip/hip_runtime.h>
#include <cstdint>
#include <cstddef>

typedef __attribute__((ext_vector_type(8))) short bf16x8;
typedef __attribute__((ext_vector_type(4))) short s16x4;
typedef __attribute__((ext_vector_type(2))) short s16x2;
typedef __attribute__((ext_vector_type(4))) float f32x4;

#define DEVI static __device__ __forceinline__

DEVI short f2bf(float f){
  unsigned u = __builtin_bit_cast(unsigned, f);
  u += 0x7fffu + ((u >> 16) & 1u);
  return (short)(u >> 16);
}

DEVI f32x4 mfma16(bf16x8 a, bf16x8 b, f32x4 c){
  return __builtin_amdgcn_mfma_f32_16x16x32_bf16(a, b, c, 0, 0, 0);
}

// ---------------- kernel 1: fp32 weights -> bf16 ----------------
__global__ __launch_bounds__(256) void k_conv(const float* __restrict__ wq, const float* __restrict__ wp,
                                              short* __restrict__ wqb, short* __restrict__ wpb){
  int t = blockIdx.x * 256 + threadIdx.x;
  for (int i = t; i < 768 * 256; i += 256 * 256) wqb[i] = f2bf(wq[i]);
  if (t < 256 * 256) wpb[t] = f2bf(wp[t]);
}

// ---------------- kernel 2: groupnorm stats ----------------
// grid = 128 (b*32+g); each group = 8 channels * 4096 = 32768 floats
__global__ __launch_bounds__(256) void k_stats(const float* __restrict__ x, float2* __restrict__ st){
  int b = blockIdx.x >> 5, g = blockIdx.x & 31;
  const f32x4* p = (const f32x4*)(x + ((size_t)(b * 256 + g * 8)) * 4096);
  float s = 0.f, ss = 0.f;
  for (int i = threadIdx.x; i < 8192; i += 256){
    f32x4 v = p[i];
    s  += v[0] + v[1] + v[2] + v[3];
    ss += v[0]*v[0] + v[1]*v[1] + v[2]*v[2] + v[3]*v[3];
  }
  for (int d = 32; d; d >>= 1){ s += __shfl_down(s, d); ss += __shfl_down(ss, d); }
  __shared__ float a0[4], a1[4];
  int w = threadIdx.x >> 6;
  if ((threadIdx.x & 63) == 0){ a0[w] = s; a1[w] = ss; }
  __syncthreads();
  if (threadIdx.x == 0){
    s = a0[0] + a0[1] + a0[2] + a0[3];
    ss = a1[0] + a1[1] + a1[2] + a1[3];
    float mean = s * (1.f / 32768.f);
    float var = ss * (1.f / 32768.f) - mean * mean;
    st[blockIdx.x] = make_float2(mean, rsqrtf(var + 1e-5f));
  }
}

// ---------------- kernel 3: normalize + transpose -> h_t (B,N,C) bf16 ----------------
// grid = B*64; block handles 64 n x 256 c, transposes via LDS for coalesced h_t writes
__global__ __launch_bounds__(256) void k_norm(const float* __restrict__ x, const float2* __restrict__ st,
                                              const float* __restrict__ gw, const float* __restrict__ gb,
                                              short* __restrict__ h_t){
  __shared__ short t[256][66];   // [c][n], pad 66
  int b = blockIdx.x >> 6;
  int n0 = (blockIdx.x & 63) * 64;
  int tid = threadIdx.x;
  for (int r = 0; r < 16; ++r){
    int idx = tid + r * 256;
    int c = idx >> 4, ch = idx & 15;
    f32x4 v = *(const f32x4*)(x + ((size_t)(b * 256 + c)) * 4096 + n0 + ch * 4);
    float2 s = st[b * 32 + (c >> 3)];
    float wv = gw[c] * s.y;
    float bv = gb[c] - s.x * wv;
    s16x2 p0, p1;
    p0[0] = f2bf(v[0] * wv + bv); p0[1] = f2bf(v[1] * wv + bv);
    p1[0] = f2bf(v[2] * wv + bv); p1[1] = f2bf(v[3] * wv + bv);
    *(s16x2*)&t[c][ch * 4]     = p0;
    *(s16x2*)&t[c][ch * 4 + 2] = p1;
  }
  __syncthreads();
  for (int r = 0; r < 8; ++r){
    int idx = tid + r * 256;
    int n = idx >> 5, cc = idx & 31;
    bf16x8 pk;
    #pragma unroll
    for (int j = 0; j < 8; ++j) pk[j] = t[cc * 8 + j][n];
    *(bf16x8*)(h_t + ((size_t)(b * 4096 + n0 + n)) * 256 + cc * 8) = pk;
  }
}

// ---------------- kernel 4/6: 128x128-tile bf16 MFMA GEMM ----------------
// A: (M x 256) bf16 row-major.  Bsrc: (B*4096 x 256) bf16 row-major (contraction over c).
// mode 0: qkv -> q_t,k_t (B,N,C) + v (B,C,N), + qkv_b
// mode 1: proj -> out = x + A@Bsrc^T + proj_b, fp32 (B,C,N)
__global__ __launch_bounds__(256) void k_gemm(const short* __restrict__ A,
                                              const short* __restrict__ Bsrc,
                                              const float* __restrict__ bias,
                                              int mtiles, int mode,
                                              short* __restrict__ q_t, short* __restrict__ k_t,
                                              short* __restrict__ v_,
                                              const float* __restrict__ xres, float* __restrict__ outp)
{
  __shared__ short a_s[128 * 72];
  __shared__ short b_s[128 * 72];
  int t = blockIdx.x;
  int mt = t % mtiles; t /= mtiles;
  int nt = t & 31; int b = t >> 5;
  int o0 = mt * 128, n0 = nt * 128;
  int tid = threadIdx.x;
  int lane = tid & 63, w = tid >> 6;
  int col = lane & 15, quad = lane >> 4;
  int wo = (w >> 1) * 64, wn = (w & 1) * 64;

  f32x4 acc[4][4];
  #pragma unroll
  for (int i = 0; i < 4; ++i)
    #pragma unroll
    for (int j = 0; j < 4; ++j)
      #pragma unroll
      for (int r = 0; r < 4; ++r) acc[i][j][r] = 0.f;

  for (int kk = 0; kk < 4; ++kk){
    int k0 = kk * 64;
    #pragma unroll
    for (int r = 0; r < 4; ++r){
      int idx = tid + r * 256;
      int row = idx >> 3, ch = idx & 7;
      *(bf16x8*)&a_s[row * 72 + ch * 8] = *(const bf16x8*)(A + (size_t)(o0 + row) * 256 + k0 + ch * 8);
      *(bf16x8*)&b_s[row * 72 + ch * 8] = *(const bf16x8*)(Bsrc + ((size_t)(b * 4096 + n0 + row)) * 256 + k0 + ch * 8);
    }
    __syncthreads();
    #pragma unroll
    for (int kc = 0; kc < 2; ++kc){
      bf16x8 af[4], bfr[4];
      #pragma unroll
      for (int i = 0; i < 4; ++i) af[i]  = *(bf16x8*)&a_s[(wo + i * 16 + col) * 72 + kc * 32 + quad * 8];
      #pragma unroll
      for (int j = 0; j < 4; ++j) bfr[j] = *(bf16x8*)&b_s[(wn + j * 16 + col) * 72 + kc * 32 + quad * 8];
      #pragma unroll
      for (int i = 0; i < 4; ++i)
        #pragma unroll
        for (int j = 0; j < 4; ++j)
          acc[i][j] = mfma16(af[i], bfr[j], acc[i][j]);
    }
    __syncthreads();
  }

  float bv[4][4];
  #pragma unroll
  for (int i = 0; i < 4; ++i)
    #pragma unroll
    for (int r = 0; r < 4; ++r) bv[i][r] = bias[o0 + wo + i * 16 + quad * 4 + r];

  if (mode == 0){
    int region = o0 >> 8;              // 0=q 1=k 2=v (block-uniform)
    int obase = (o0 & 255) + wo;
    if (region < 2){
      short* dst = region ? k_t : q_t;
      #pragma unroll
      for (int i = 0; i < 4; ++i)
        #pragma unroll
        for (int j = 0; j < 4; ++j){
          int n = n0 + wn + j * 16 + col;
          s16x4 pk;
          #pragma unroll
          for (int r = 0; r < 4; ++r) pk[r] = f2bf(acc[i][j][r] + bv[i][r]);
          *(s16x4*)(dst + ((size_t)(b * 4096 + n)) * 256 + obase + i * 16 + quad * 4) = pk;
        }
    } else {
      #pragma unroll
      for (int i = 0; i < 4; ++i)
        #pragma unroll
        for (int r = 0; r < 4; ++r){
          int oo = obase + i * 16 + quad * 4 + r;
          #pragma unroll
          for (int j = 0; j < 4; ++j){
            int n = n0 + wn + j * 16 + col;
            v_[((size_t)(b * 256 + oo)) * 4096 + n] = f2bf(acc[i][j][r] + bv[i][r]);
          }
        }
    }
  } else {
    #pragma unroll
    for (int i = 0; i < 4; ++i)
      #pragma unroll
      for (int r = 0; r < 4; ++r){
        int oo = o0 + wo + i * 16 + quad * 4 + r;
        #pragma unroll
        for (int j = 0; j < 4; ++j){
          int n = n0 + wn + j * 16 + col;
          size_t off = ((size_t)(b * 256 + oo)) * 4096 + n;
          outp[off] = xres[off] + acc[i][j][r] + bv[i][r];
        }
      }
  }
}

// ---------------- kernel 5: flash attention ----------------
// grid = B*64; block = 64 q-rows (16/wave), BM=32 K/V tiles, online softmax
__global__ __launch_bounds__(256) void k_attn(const short* __restrict__ q_t, const short* __restrict__ k_t,
                                              const short* __restrict__ v_, short* __restrict__ o_t)
{
  __shared__ short k_s[32 * 264];     // [m][c] pad 264
  __shared__ short v_s[256 * 40];     // [c][m] pad 40
  __shared__ short p_s[4 * 16 * 40];  // per-wave [row][m] pad 40
  int b = blockIdx.x >> 6;
  int q0 = (blockIdx.x & 63) * 64;
  int tid = threadIdx.x, lane = tid & 63, w = tid >> 6;
  int col = lane & 15, quad = lane >> 4;

  // Q fragments straight from global (A-layout: row=lane&15, k=quad*8+j)
  bf16x8 qf[8];
  const short* qrow = q_t + ((size_t)(b * 4096 + q0 + w * 16 + col)) * 256;
  #pragma unroll
  for (int kc = 0; kc < 8; ++kc) qf[kc] = *(const bf16x8*)(qrow + kc * 32 + quad * 8);

  f32x4 o_acc[16];
  #pragma unroll
  for (int i = 0; i < 16; ++i)
    #pragma unroll
    for (int r = 0; r < 4; ++r) o_acc[i][r] = 0.f;
  float m_r[4] = {-1e30f, -1e30f, -1e30f, -1e30f};
  float l_r[4] = {0.f, 0.f, 0.f, 0.f};

  #pragma unroll 1
  for (int mt = 0; mt < 128; ++mt){
    int m0 = mt * 32;
    #pragma unroll
    for (int r = 0; r < 4; ++r){
      int idx = tid + r * 256;
      { int row = idx >> 5, ch = idx & 31;
        *(bf16x8*)&k_s[row * 264 + ch * 8] = *(const bf16x8*)(k_t + ((size_t)(b * 4096 + m0 + row)) * 256 + ch * 8); }
      { int row = idx >> 2, ch = idx & 3;
        *(bf16x8*)&v_s[row * 40 + ch * 8] = *(const bf16x8*)(v_ + ((size_t)(b * 256 + row)) * 4096 + m0 + ch * 8); }
    }
    __syncthreads();

    // S = Q K^T  (16 q-rows x 32 m per wave)
    f32x4 s_acc[2];
    #pragma unroll
    for (int i = 0; i < 2; ++i)
      #pragma unroll
      for (int r = 0; r < 4; ++r) s_acc[i][r] = 0.f;
    #pragma unroll
    for (int mtile = 0; mtile < 2; ++mtile)
      #pragma unroll
      for (int kc = 0; kc < 8; ++kc){
        bf16x8 kb = *(bf16x8*)&k_s[(mtile * 16 + col) * 264 + kc * 32 + quad * 8];
        s_acc[mtile] = mfma16(qf[kc], kb, s_acc[mtile]);
      }

    // online softmax (stats within 16-lane quad groups)
    float alpha[4];
    #pragma unroll
    for (int r = 0; r < 4; ++r){
      float s0 = s_acc[0][r] * 0.0625f, s1 = s_acc[1][r] * 0.0625f;
      float mx = fmaxf(s0, s1);
      #pragma unroll
      for (int d = 1; d < 16; d <<= 1) mx = fmaxf(mx, __shfl_xor(mx, d));
      float mn = fmaxf(m_r[r], mx);
      alpha[r] = __expf(m_r[r] - mn);
      m_r[r] = mn;
      float p0 = __expf(s0 - mn), p1 = __expf(s1 - mn);
      s_acc[0][r] = p0; s_acc[1][r] = p1;
      float rs = p0 + p1;
      #pragma unroll
      for (int d = 1; d < 16; d <<= 1) rs += __shfl_xor(rs, d);
      l_r[r] = l_r[r] * alpha[r] + rs;
    }
    #pragma unroll
    for (int i = 0; i < 16; ++i)
      #pragma unroll
      for (int r = 0; r < 4; ++r) o_acc[i][r] *= alpha[r];

    // P: C-layout -> LDS -> A-layout (wave-local region, no barrier needed)
    short* pw = &p_s[w * 640];
    #pragma unroll
    for (int mtile = 0; mtile < 2; ++mtile)
      #pragma unroll
      for (int r = 0; r < 4; ++r)
        pw[(quad * 4 + r) * 40 + mtile * 16 + col] = f2bf(s_acc[mtile][r]);
    bf16x8 pf = *(bf16x8*)&pw[col * 40 + quad * 8];

    // O += P V
    #pragma unroll
    for (int ct = 0; ct < 16; ++ct){
      bf16x8 vf = *(bf16x8*)&v_s[(ct * 16 + col) * 40 + quad * 8];
      o_acc[ct] = mfma16(pf, vf, o_acc[ct]);
    }
    __syncthreads();
  }

  float inv[4];
  #pragma unroll
  for (int r = 0; r < 4; ++r) inv[r] = 1.f / l_r[r];
  #pragma unroll
  for (int ct = 0; ct < 16; ++ct)
    #pragma unroll
    for (int r = 0; r < 4; ++r)
      o_t[((size_t)(b * 4096 + q0 + w * 16 + quad * 4 + r)) * 256 + ct * 16 + col] = f2bf(o_acc[ct][r] * inv[r]);
}

extern "C" void kernel_launch(void* const* d_in, const int* in_sizes, int n_in,
                              void* d_out, int out_size, void* d_ws, size_t ws_size,
                              hipStream_t stream)
{
  const float* x     = (const float*)d_in[0];
  const float* gw    = (const float*)d_in[1];
  const float* gb    = (const float*)d_in[2];
  const float* qkvw  = (const float*)d_in[3];
  const float* qkvb  = (const float*)d_in[4];
  const float* projw = (const float*)d_in[5];
  const float* projb = (const float*)d_in[6];
  float* out = (float*)d_out;

  char* ws = (char*)d_ws;
  float2* stats = (float2*)ws;                         // 1 KB
  short* wqb = (short*)(ws + 1024);                    // 768*256*2 = 384 KB
  short* wpb = (short*)(ws + 1024 + 393216);           // 128 KB
  short* h_t = (short*)(ws + 1024 + 393216 + 131072);  // big buffers, 8 MB each
  const size_t BIG = (size_t)4 * 4096 * 256;           // elements
  short* q_t = h_t + BIG;
  short* k_t = q_t + BIG;
  short* v_  = k_t + BIG;
  short* o_t = v_  + BIG;

  k_conv <<<dim3(256), dim3(256), 0, stream>>>(qkvw, projw, wqb, wpb);
  k_stats<<<dim3(128), dim3(256), 0, stream>>>(x, stats);
  k_norm <<<dim3(256), dim3(256), 0, stream>>>(x, stats, gw, gb, h_t);
  k_gemm <<<dim3(768), dim3(256), 0, stream>>>(wqb, h_t, qkvb, 6, 0, q_t, k_t, v_,
                                               (const float*)nullptr, (float*)nullptr);
  k_attn <<<dim3(256), dim3(256), 0, stream>>>(q_t, k_t, v_, o_t);
  k_gemm <<<dim3(256), dim3(256), 0, stream>>>(wpb, o_t, projb, 2, 1,
                                               (short*)nullptr, (short*)nullptr, (short*)nullptr,
                                               x, out);
}